// Round 8
// baseline (1045.079 us; speedup 1.0000x reference)
//
#include <hip/hip_runtime.h>
#include <hip/hip_bf16.h>

// ---- problem dims (fixed) ----
#define Bdim 4
#define Ldim 512
#define Ddim 768
#define Kspan 96
#define Hdim 3072
#define Pdim 9120      // Kspan*(Kspan-1)
#define MROWS 384      // Bdim*Kspan
#define NT6 96         // Hdim/32: K-tiles for pair kernel (BK=32)

typedef __bf16 bf16x8 __attribute__((ext_vector_type(8)));
typedef float f32x4 __attribute__((ext_vector_type(4)));
typedef float f32x16 __attribute__((ext_vector_type(16)));
typedef unsigned short ushort8v __attribute__((ext_vector_type(8)));

static __device__ __forceinline__ unsigned short f2bf(float x){
  return __builtin_bit_cast(unsigned short, (__bf16)x);
}
static __device__ __forceinline__ float bf2f(unsigned short u){
  return (float)__builtin_bit_cast(__bf16, u);
}
static __device__ __forceinline__ float bfbits2f(unsigned short u){
  return __builtin_bit_cast(float, (unsigned)u << 16);
}

// ---------------- merged transpose+split: W[K][N] f32 -> WT[N][K] bf16 hi+lo -------------
struct TJob { const float* W; unsigned short* Th; unsigned short* Tl; int K; int N; int base; };
struct TJobs { TJob j[7]; };

__global__ __launch_bounds__(256) void transpose_multi(TJobs JJ)
{
  int x = blockIdx.x;
  int ji = 0;
  #pragma unroll
  for (int q = 1; q < 7; q++) if (x >= JJ.j[q].base) ji = q;
  TJob J = JJ.j[ji];
  int local = x - J.base;
  int tilesX = J.N >> 6;
  int bx = local % tilesX, by = local / tilesX;
  __shared__ float tile[64][65];
  int k0 = by * 64, n0 = bx * 64;
  int c = threadIdx.x & 63, r0 = threadIdx.x >> 6;
  for (int p = 0; p < 16; p++){
    int r = r0 + p * 4;
    tile[c][r] = J.W[(size_t)(k0 + r) * J.N + n0 + c];
  }
  __syncthreads();
  for (int p = 0; p < 16; p++){
    int n = r0 + p * 4;
    float xv = tile[n][c];
    unsigned short h = f2bf(xv);
    size_t o = (size_t)(n0 + n) * J.K + k0 + c;
    J.Th[o] = h;
    J.Tl[o] = f2bf(xv - bf2f(h));
  }
}

// ---------------- pack ro_w2 [Hdim][Ddim] f32 -> W2B bf16 fragment-packed ----------------
// Tile (nq in 0..5, kt in 0..95) = 4096 shorts: [wn 2][kh 2][nf 2][hsel 2][l31 32][e 8]
// maps to W[k = kt*32 + (kh*2+hsel)*8 + e][n = nq*128 + wn*64 + nf*32 + l31].
// A wave's b128 load (lane = hsel*32+l31) covers 1024B contiguous; kh/nf are imm offsets.
__global__ __launch_bounds__(256) void pack_w2(
    const float* __restrict__ W, unsigned short* __restrict__ W2B)
{
  __shared__ float tile[32][129];
  int kt = blockIdx.x, nq = blockIdx.y, t = threadIdx.x;
  for (int q = 0; q < 16; q++){
    int flat = q * 256 + t;             // 0..4095
    int kl = flat >> 7, n = flat & 127;
    tile[kl][n] = W[(size_t)(kt * 32 + kl) * Ddim + nq * 128 + n];
  }
  __syncthreads();
  unsigned short* outp = W2B + (size_t)(nq * 96 + kt) * 4096;
  for (int q = 0; q < 16; q++){
    int o = q * 256 + t;
    int wn = (o >> 11) & 1, kh = (o >> 10) & 1, nf = (o >> 9) & 1;
    int hs = (o >> 8) & 1, l31 = (o >> 3) & 31, e = o & 7;
    int nl = wn * 64 + nf * 32 + l31;
    int kl = (kh * 2 + hs) * 8 + e;
    outp[o] = f2bf(tile[kl][nl]);
  }
}

// ---------------- gather h rows at span indices (fp32 copy) ----------------
__global__ __launch_bounds__(256) void gather_rows(
    const float* __restrict__ h, const int* __restrict__ span, float* __restrict__ hg)
{
  int x = blockIdx.x;            // 0 .. 2*MROWS-1
  int sel = (x >= MROWS) ? 1 : 0;
  int r = x - sel * MROWS;
  int b = r / Kspan, k = r - b * Kspan;
  int idx = span[(b * Kspan + k) * 2 + sel];
  const float* src = h + ((size_t)b * Ldim + idx) * Ddim;
  float* dst = hg + (size_t)x * Ddim;
  for (int d = threadIdx.x; d < Ddim; d += 256) dst[d] = src[d];
}

// ---------------- split-bf16 GEMM (multi-job + optional split-K) ------------------------
// MODE 0: relu(acc+bias) f32; MODE 1: acc+bias f32; MODE 2: raw split-K partial;
// MODE 6: both jobs -> bf16 (job0 with bias, job1 raw) — U/V production.
struct GJob {
  const float* A;
  const unsigned short* Wh;
  const unsigned short* Wl;
  const float* bias;
  float* C;
};

template<int MODE, int SPLIT>
__global__ __launch_bounds__(256) void gemm_ms(
    GJob j0, GJob j1, int ldA, int ldW, int ldC, int kLen, size_t csz)
{
  constexpr int SR = 40;
  __shared__ __align__(16) unsigned short Ah[64 * SR], Al[64 * SR];
  __shared__ __align__(16) unsigned short Bh[128 * SR], Bl[128 * SR];
  int zj, s;
  if (SPLIT == 1){ zj = blockIdx.z; s = 0; }
  else { zj = blockIdx.z / SPLIT; s = blockIdx.z % SPLIT; }
  const GJob J = zj ? j1 : j0;
  int kBegin = s * kLen;
  float* Cptr = (MODE == 2) ? (J.C + (size_t)s * csz) : J.C;

  int m0 = blockIdx.y * 64, n0 = blockIdx.x * 128;
  int t = threadIdx.x, lane = t & 63, wid = t >> 6;
  int wm = wid >> 1, wn = wid & 1;
  int lr = lane & 15, lk = (lane >> 4) * 8;
  f32x4 acc[2][4] = {};
  int ar = t >> 2, akq = t & 3;
  for (int k0 = 0; k0 < kLen; k0 += 32){
    {
      const float* sp = J.A + (size_t)(m0 + ar) * ldA + kBegin + k0 + akq * 8;
      f32x4 x0 = *(const f32x4*)sp, x1 = *(const f32x4*)(sp + 4);
      ushort8v vh, vl;
      for (int e = 0; e < 4; e++){ float x = x0[e]; unsigned short hh = f2bf(x); vh[e] = hh; vl[e] = f2bf(x - bf2f(hh)); }
      for (int e = 0; e < 4; e++){ float x = x1[e]; unsigned short hh = f2bf(x); vh[e+4] = hh; vl[e+4] = f2bf(x - bf2f(hh)); }
      *(ushort8v*)&Ah[ar * SR + akq * 8] = vh;
      *(ushort8v*)&Al[ar * SR + akq * 8] = vl;
    }
    for (int p = 0; p < 2; p++){
      int idx = p * 256 + t; int n = idx >> 2, kq = idx & 3;
      size_t go = (size_t)(n0 + n) * ldW + kBegin + k0 + kq * 8;
      *(ushort8v*)&Bh[n * SR + kq * 8] = *(const ushort8v*)(J.Wh + go);
      *(ushort8v*)&Bl[n * SR + kq * 8] = *(const ushort8v*)(J.Wl + go);
    }
    __syncthreads();
    bf16x8 ah[2], al2[2], bh[4], bl[4];
    for (int f = 0; f < 2; f++){ int o = (wm * 32 + f * 16 + lr) * SR + lk; ah[f] = *(const bf16x8*)&Ah[o]; al2[f] = *(const bf16x8*)&Al[o]; }
    for (int g = 0; g < 4; g++){ int o = (wn * 64 + g * 16 + lr) * SR + lk; bh[g] = *(const bf16x8*)&Bh[o]; bl[g] = *(const bf16x8*)&Bl[o]; }
    for (int f = 0; f < 2; f++)
      for (int g = 0; g < 4; g++){
        acc[f][g] = __builtin_amdgcn_mfma_f32_16x16x32_bf16(ah[f],  bh[g], acc[f][g], 0, 0, 0);
        acc[f][g] = __builtin_amdgcn_mfma_f32_16x16x32_bf16(ah[f],  bl[g], acc[f][g], 0, 0, 0);
        acc[f][g] = __builtin_amdgcn_mfma_f32_16x16x32_bf16(al2[f], bh[g], acc[f][g], 0, 0, 0);
      }
    __syncthreads();
  }
  int rr = (lane >> 4) * 4;
  for (int f = 0; f < 2; f++){
    int gm = m0 + wm * 32 + f * 16 + rr;
    for (int g = 0; g < 4; g++){
      int gn = n0 + wn * 64 + g * 16 + (lane & 15);
      float bv = (MODE != 2 && J.bias) ? J.bias[gn] : 0.f;
      for (int r2 = 0; r2 < 4; r2++){
        float v = acc[f][g][r2] + bv;
        if (MODE == 0) v = fmaxf(v, 0.f);
        if (MODE == 6){
          ((unsigned short*)J.C)[(size_t)(gm + r2) * ldC + gn] = f2bf(v);
        } else {
          Cptr[(size_t)(gm + r2) * ldC + gn] = v;
        }
      }
    }
  }
}

// ---------------- split-K partial reduce ----------------
template<bool RELU>
__global__ __launch_bounds__(256) void reduce_part(
    const float* __restrict__ P, int S,
    const float* __restrict__ bias0, const float* __restrict__ bias1,
    float* __restrict__ outp, int zCount, int ldOut)
{
  const int MN = MROWS * Ddim;
  int idx4 = blockIdx.x * 256 + threadIdx.x;
  int flat = idx4 * 4;
  if (flat >= MN * zCount) return;
  int z = flat / MN; int rem = flat - z * MN;
  int r = rem / Ddim; int c = rem - r * Ddim;
  const float* base = P + (size_t)z * S * MN + rem;
  f32x4 sv = *(const f32x4*)base;
  for (int ss = 1; ss < S; ss++){ f32x4 v = *(const f32x4*)(base + (size_t)ss * MN); sv += v; }
  const float* bp = z ? bias1 : bias0;
  f32x4 bv = *(const f32x4*)(bp + c);
  sv += bv;
  if (RELU) for (int e = 0; e < 4; e++) sv[e] = fmaxf(sv[e], 0.f);
  *(f32x4*)(outp + (size_t)r * ldOut + z * Ddim + c) = sv;
}

// ---------------- fused pair GEMM v8 --------------------------------------------------
// LDS-traffic-minimized: LDS holds ONLY the A tile (2 x 12 KiB dbuf).  B weights go
// global(L2)->registers via frag-packed W2B; U/V go global->registers (bf16).  Per CU
// per phase: LDS ~72 b128 ops (~864 cy) vs MFMA 776 cy/SIMD -- balanced, vs v7's 1950.
// Register ping-pong at distance 2 (B via tmp to avoid same-phase WAR).  One barrier
// per phase; all global loads get a full phase before the barrier drain.
__global__ __launch_bounds__(256, 2) void pair_gemm8(
    const unsigned short* __restrict__ Ub,  // [MROWS][Hdim] bf16, ro_b1 folded
    const unsigned short* __restrict__ Vp,  // [MROWS][Hdim] bf16
    const unsigned short* __restrict__ W2B, // frag-packed per (nq,kt), 4096 shorts
    const float* __restrict__ b2,           // [Ddim]
    float* __restrict__ out)                // [Bdim*Pdim][Ddim]
{
  __shared__ __align__(16) unsigned short As[2][192 * 32]; // 2 x 12 KiB

  int x = blockIdx.x;
  int xcd = x & 7;
  int s = x >> 3;                 // 0..143
  int grp = s / 48;
  int ig  = s - grp * 48;
  int combo = xcd + grp * 8;      // 0..23
  int nq = combo % 6, b = combo / 6;

  int t = threadIdx.x, lane = t & 63, w = t >> 6;
  int wm = w >> 1, wn = w & 1;
  int l31 = lane & 31, hsel = lane >> 5;
  int i0 = ig * 2, i = i0 + wm;

  // builder: 3 items, row = t/4 + 64q, fixed granule bg = t&3
  int brow = t >> 2, bg = t & 3;
  int vj[3], ih[3];
  #pragma unroll
  for (int q = 0; q < 3; q++){
    int r = brow + 64 * q;
    vj[q] = (r >= 96) ? (r - 96) : r;
    ih[q] = (r >= 96) ? 1 : 0;
  }

  f32x16 acc[3][2] = {};
  ushort8v vE[3], vO[3], uE[2], uO[2], bE[4], bO[4];

  const unsigned short* Vbase = Vp + (size_t)(b * 96) * Hdim + bg * 8;
  const unsigned short* Ubase = Ub + (size_t)(b * 96 + i0) * Hdim + bg * 8;
  const unsigned short* Wt = W2B + (size_t)(nq * 96) * 4096 + wn * 2048 + hsel * 256 + l31 * 8;

  auto loadVU = [&](int kt, ushort8v* v, ushort8v* u){
    #pragma unroll
    for (int q = 0; q < 3; q++)
      v[q] = *(const ushort8v*)(Vbase + (size_t)vj[q] * Hdim + kt * 32);
    u[0] = *(const ushort8v*)(Ubase + kt * 32);
    u[1] = *(const ushort8v*)(Ubase + Hdim + kt * 32);
  };
  auto loadB = [&](int kt, ushort8v* dst){
    const unsigned short* p = Wt + (size_t)kt * 4096;
    dst[0] = *(const ushort8v*)(p);
    dst[1] = *(const ushort8v*)(p + 512);
    dst[2] = *(const ushort8v*)(p + 1024);
    dst[3] = *(const ushort8v*)(p + 1536);
  };
  auto build = [&](int buf, const ushort8v* v, const ushort8v* u){
    float uf[2][8];
    #pragma unroll
    for (int h2 = 0; h2 < 2; h2++)
      #pragma unroll
      for (int e = 0; e < 8; e++) uf[h2][e] = bfbits2f(u[h2][e]);
    unsigned short* dp = (buf == 0) ? &As[0][0] : &As[1][0];
    #pragma unroll
    for (int q = 0; q < 3; q++){
      int r = brow + 64 * q;
      ushort8v vv = v[q];
      ushort8v pk;
      #pragma unroll
      for (int e = 0; e < 8; e++)
        pk[e] = f2bf(fmaxf(uf[ih[q]][e] + bfbits2f(vv[e]), 0.f));
      *(ushort8v*)(dp + r * 32 + ((bg ^ ((r >> 1) & 3)) << 3)) = pk;
    }
  };
  auto compute = [&](int buf, const ushort8v* bfrag){
    const unsigned short* ap = (buf == 0) ? &As[0][0] : &As[1][0];
    #pragma unroll
    for (int kh = 0; kh < 2; kh++){
      int g = kh * 2 + hsel;
      bf16x8 afr[3];
      #pragma unroll
      for (int mf = 0; mf < 3; mf++){
        int r = wm * 96 + mf * 32 + l31;
        afr[mf] = *(const bf16x8*)(ap + r * 32 + ((g ^ ((r >> 1) & 3)) << 3));
      }
      #pragma unroll
      for (int mf = 0; mf < 3; mf++)
        #pragma unroll
        for (int nf = 0; nf < 2; nf++)
          acc[mf][nf] = __builtin_amdgcn_mfma_f32_32x32x16_bf16(
              afr[mf], __builtin_bit_cast(bf16x8, bfrag[kh * 2 + nf]), acc[mf][nf], 0, 0, 0);
    }
  };

  // prologue: loads for tiles 0,1; build(0)
  loadVU(0, vE, uE); loadB(0, bE);
  loadVU(1, vO, uO); loadB(1, bO);
  build(0, vE, uE);
  __syncthreads();               // As[0] visible

  for (int kt = 0; kt < NT6; kt += 2){
    // even phase: compute(kt) from As[0]+bE; build(kt+1)->As[1]; load tile kt+2
    ushort8v tb[4];
    if (kt + 2 < NT6){ loadVU(kt + 2, vE, uE); loadB(kt + 2, tb); }
    if (kt + 1 < NT6) build(1, vO, uO);
    compute(0, bE);
    if (kt + 2 < NT6){
      #pragma unroll
      for (int q = 0; q < 4; q++) bE[q] = tb[q];
    }
    __syncthreads();
    // odd phase
    int ko = kt + 1;
    if (ko + 2 < NT6){ loadVU(ko + 2, vO, uO); loadB(ko + 2, tb); }
    if (ko + 1 < NT6) build(0, vE, uE);
    compute(1, bO);
    if (ko + 2 < NT6){
      #pragma unroll
      for (int q = 0; q < 4; q++) bO[q] = tb[q];
    }
    __syncthreads();
  }

  // epilogue: wave wm -> i; row j -> pair p = i*95 + j - (j>i); skip j==i
  size_t outB = (size_t)b * Pdim;
  int colbase = nq * 128 + wn * 64;
  float bc[2];
  #pragma unroll
  for (int nf = 0; nf < 2; nf++) bc[nf] = b2[colbase + nf * 32 + l31];
  #pragma unroll
  for (int mf = 0; mf < 3; mf++){
    #pragma unroll
    for (int reg = 0; reg < 16; reg++){
      int j = mf * 32 + (reg & 3) + 8 * (reg >> 2) + 4 * hsel;
      if (j == i) continue;
      int p = i * 95 + j - (j > i ? 1 : 0);
      float* orow = out + (outB + p) * Ddim + colbase;
      #pragma unroll
      for (int nf = 0; nf < 2; nf++)
        orow[nf * 32 + l31] = acc[mf][nf][reg] + bc[nf];
    }
  }
}

// ---------------- host launch ----------------
extern "C" void kernel_launch(void* const* d_in, const int* in_sizes, int n_in,
                              void* d_out, int out_size, void* d_ws, size_t ws_size,
                              hipStream_t stream)
{
  (void)in_sizes; (void)n_in; (void)out_size;
  const float* h     = (const float*)d_in[0];
  const int*   span  = (const int*)d_in[1];
  const float* ps_w1 = (const float*)d_in[2];
  const float* ps_b1 = (const float*)d_in[3];
  const float* ps_w2 = (const float*)d_in[4];
  const float* ps_b2 = (const float*)d_in[5];
  const float* pe_w1 = (const float*)d_in[6];
  const float* pe_b1 = (const float*)d_in[7];
  const float* pe_w2 = (const float*)d_in[8];
  const float* pe_b2 = (const float*)d_in[9];
  const float* so_w1 = (const float*)d_in[10];
  const float* so_b1 = (const float*)d_in[11];
  const float* so_w2 = (const float*)d_in[12];
  const float* so_b2 = (const float*)d_in[13];
  const float* ro_w1 = (const float*)d_in[14];
  const float* ro_b1 = (const float*)d_in[15];
  const float* ro_w2 = (const float*)d_in[16];
  const float* ro_b2 = (const float*)d_in[17];

  char* ws = (char*)d_ws;
  size_t off = 0;
  auto alloc_us = [&](size_t n)->unsigned short*{
    unsigned short* p = (unsigned short*)(ws + off);
    off += ((n * 2 + 255) & ~(size_t)255);
    return p;
  };
  auto alloc_f = [&](size_t n)->float*{
    float* p = (float*)(ws + off);
    off += ((n * 4 + 255) & ~(size_t)255);
    return p;
  };

  unsigned short* ps1h = alloc_us((size_t)Hdim * Ddim); unsigned short* ps1l = alloc_us((size_t)Hdim * Ddim);
  unsigned short* ps2h = alloc_us((size_t)Ddim * Hdim); unsigned short* ps2l = alloc_us((size_t)Ddim * Hdim);
  unsigned short* pe1h = alloc_us((size_t)Hdim * Ddim); unsigned short* pe1l = alloc_us((size_t)Hdim * Ddim);
  unsigned short* pe2h = alloc_us((size_t)Ddim * Hdim); unsigned short* pe2l = alloc_us((size_t)Ddim * Hdim);
  unsigned short* so1h = alloc_us((size_t)Hdim * 2 * Ddim); unsigned short* so1l = alloc_us((size_t)Hdim * 2 * Ddim);
  unsigned short* so2h = alloc_us((size_t)Ddim * Hdim); unsigned short* so2l = alloc_us((size_t)Ddim * Hdim);
  unsigned short* ro1h = alloc_us((size_t)Hdim * 2 * Ddim); unsigned short* ro1l = alloc_us((size_t)Hdim * 2 * Ddim);
  unsigned short* W2B  = alloc_us((size_t)6 * 96 * 4096);   // 2.36M shorts
  unsigned short* Vp   = alloc_us((size_t)MROWS * Hdim);    // bf16 V
  unsigned short* Ub   = alloc_us((size_t)MROWS * Hdim);    // bf16 U (ro_b1 folded)
  float* hg     = alloc_f((size_t)2 * MROWS * Ddim);
  float* mid_s  = alloc_f((size_t)MROWS * Hdim);
  float* mid_e  = alloc_f((size_t)MROWS * Hdim);
  float* cat    = alloc_f((size_t)MROWS * 2 * Ddim);
  float* entity = alloc_f((size_t)MROWS * Ddim);
  const size_t MN = (size_t)MROWS * Ddim;
  float* P2 = alloc_f(8 * MN);
  float* P3 = alloc_f(8 * MN);
  if (off > ws_size) return;

  dim3 tb(256);

  // merged weight transposes (7 jobs)
  {
    TJobs JJ;
    int base = 0;
    auto add = [&](int idx, const float* W, unsigned short* Th, unsigned short* Tl, int K, int N){
      JJ.j[idx] = TJob{W, Th, Tl, K, N, base};
      base += (N / 64) * (K / 64);
    };
    add(0, ps_w1, ps1h, ps1l, Ddim, Hdim);
    add(1, ps_w2, ps2h, ps2l, Hdim, Ddim);
    add(2, pe_w1, pe1h, pe1l, Ddim, Hdim);
    add(3, pe_w2, pe2h, pe2l, Hdim, Ddim);
    add(4, so_w1, so1h, so1l, 2 * Ddim, Hdim);
    add(5, so_w2, so2h, so2l, Hdim, Ddim);
    add(6, ro_w1, ro1h, ro1l, 2 * Ddim, Hdim);
    transpose_multi<<<base, tb, 0, stream>>>(JJ);
  }
  pack_w2<<<dim3(NT6, 6), tb, 0, stream>>>(ro_w2, W2B);

  gather_rows<<<2 * MROWS, tb, 0, stream>>>(h, span, hg);

  // L1: start/end first linear (merged), M=384 N=3072 K=768
  {
    GJob j0{hg,                      ps1h, ps1l, ps_b1, mid_s};
    GJob j1{hg + (size_t)MROWS*Ddim, pe1h, pe1l, pe_b1, mid_e};
    gemm_ms<0,1><<<dim3(Hdim/128, MROWS/64, 2), tb, 0, stream>>>(j0, j1, Ddim, Ddim, Hdim, Ddim, 0);
  }
  // L2: start/end second linear (merged, split-K=4) -> partials
  {
    GJob j0{mid_s, ps2h, ps2l, nullptr, P2};
    GJob j1{mid_e, pe2h, pe2l, nullptr, P2 + 4*MN};
    gemm_ms<2,4><<<dim3(Ddim/128, MROWS/64, 8), tb, 0, stream>>>(j0, j1, Hdim, Hdim, Ddim, Hdim/4, MN);
  }
  reduce_part<true><<<(2*(int)MN)/1024, tb, 0, stream>>>(P2, 4, ps_b2, pe_b2, cat, 2, 2*Ddim);
  // so1: M=384 N=3072 K=1536
  {
    GJob j0{cat, so1h, so1l, so_b1, mid_s};
    gemm_ms<0,1><<<dim3(Hdim/128, MROWS/64, 1), tb, 0, stream>>>(j0, j0, 2*Ddim, 2*Ddim, Hdim, 2*Ddim, 0);
  }
  // so2: split-K=8 -> partials (no relu on entity)
  {
    GJob j0{mid_s, so2h, so2l, nullptr, P3};
    gemm_ms<2,8><<<dim3(Ddim/128, MROWS/64, 8), tb, 0, stream>>>(j0, j0, Hdim, Hdim, Ddim, Hdim/8, MN);
  }
  reduce_part<false><<<((int)MN)/1024, tb, 0, stream>>>(P3, 8, so_b2, so_b2, entity, 1, Ddim);
  // U = entity @ ro_w1_top + ro_b1 ; V = entity @ ro_w1_bot — both bf16 (MODE 6)
  {
    GJob j0{entity, ro1h,        ro1l,        ro_b1,  (float*)Ub};
    GJob j1{entity, ro1h + Ddim, ro1l + Ddim, nullptr, (float*)Vp};
    gemm_ms<6,1><<<dim3(Hdim/128, MROWS/64, 2), tb, 0, stream>>>(j0, j1, Ddim, 2*Ddim, Hdim, Ddim, 0);
  }

  // fused pair GEMM v8
  pair_gemm8<<<1152, tb, 0, stream>>>(Ub, Vp, W2B, ro_b2, (float*)d_out);
}

// Round 9
// 463.025 us; speedup vs baseline: 2.2571x; 2.2571x over previous
//
#include <hip/hip_runtime.h>
#include <hip/hip_bf16.h>

// ---- problem dims (fixed) ----
#define Bdim 4
#define Ldim 512
#define Ddim 768
#define Kspan 96
#define Hdim 3072
#define Pdim 9120      // Kspan*(Kspan-1)
#define MROWS 384      // Bdim*Kspan
#define NT6 96         // Hdim/32: K-tiles for pair kernel (BK=32)

typedef __bf16 bf16x8 __attribute__((ext_vector_type(8)));
typedef float f32x4 __attribute__((ext_vector_type(4)));
typedef float f32x16 __attribute__((ext_vector_type(16)));
typedef unsigned short ushort8v __attribute__((ext_vector_type(8)));

static __device__ __forceinline__ unsigned short f2bf(float x){
  return __builtin_bit_cast(unsigned short, (__bf16)x);
}
static __device__ __forceinline__ float bf2f(unsigned short u){
  return (float)__builtin_bit_cast(__bf16, u);
}
static __device__ __forceinline__ float bfbits2f(unsigned short u){
  return __builtin_bit_cast(float, (unsigned)u << 16);
}

// ---------------- merged transpose+split: W[K][N] f32 -> WT[N][K] bf16 hi+lo -------------
struct TJob { const float* W; unsigned short* Th; unsigned short* Tl; int K; int N; int base; };
struct TJobs { TJob j[7]; };

__global__ __launch_bounds__(256) void transpose_multi(TJobs JJ)
{
  int x = blockIdx.x;
  int ji = 0;
  #pragma unroll
  for (int q = 1; q < 7; q++) if (x >= JJ.j[q].base) ji = q;
  TJob J = JJ.j[ji];
  int local = x - J.base;
  int tilesX = J.N >> 6;
  int bx = local % tilesX, by = local / tilesX;
  __shared__ float tile[64][65];
  int k0 = by * 64, n0 = bx * 64;
  int c = threadIdx.x & 63, r0 = threadIdx.x >> 6;
  for (int p = 0; p < 16; p++){
    int r = r0 + p * 4;
    tile[c][r] = J.W[(size_t)(k0 + r) * J.N + n0 + c];
  }
  __syncthreads();
  for (int p = 0; p < 16; p++){
    int n = r0 + p * 4;
    float xv = tile[n][c];
    unsigned short h = f2bf(xv);
    size_t o = (size_t)(n0 + n) * J.K + k0 + c;
    J.Th[o] = h;
    J.Tl[o] = f2bf(xv - bf2f(h));
  }
}

// ---------------- pack ro_w2 [Hdim][Ddim] f32 -> W2B bf16 fragment-packed ----------------
// Tile (nq in 0..5, kt in 0..95) = 4096 shorts: [wn 2][kh 2][nf 2][hsel 2][l31 32][e 8]
// maps to W[k = kt*32 + (kh*2+hsel)*8 + e][n = nq*128 + wn*64 + nf*32 + l31].
__global__ __launch_bounds__(256) void pack_w2(
    const float* __restrict__ W, unsigned short* __restrict__ W2B)
{
  __shared__ float tile[32][129];
  int kt = blockIdx.x, nq = blockIdx.y, t = threadIdx.x;
  for (int q = 0; q < 16; q++){
    int flat = q * 256 + t;             // 0..4095
    int kl = flat >> 7, n = flat & 127;
    tile[kl][n] = W[(size_t)(kt * 32 + kl) * Ddim + nq * 128 + n];
  }
  __syncthreads();
  unsigned short* outp = W2B + (size_t)(nq * 96 + kt) * 4096;
  for (int q = 0; q < 16; q++){
    int o = q * 256 + t;
    int wn = (o >> 11) & 1, kh = (o >> 10) & 1, nf = (o >> 9) & 1;
    int hs = (o >> 8) & 1, l31 = (o >> 3) & 31, e = o & 7;
    int nl = wn * 64 + nf * 32 + l31;
    int kl = (kh * 2 + hs) * 8 + e;
    outp[o] = f2bf(tile[kl][nl]);
  }
}

// ---------------- gather h rows at span indices (fp32 copy) ----------------
__global__ __launch_bounds__(256) void gather_rows(
    const float* __restrict__ h, const int* __restrict__ span, float* __restrict__ hg)
{
  int x = blockIdx.x;            // 0 .. 2*MROWS-1
  int sel = (x >= MROWS) ? 1 : 0;
  int r = x - sel * MROWS;
  int b = r / Kspan, k = r - b * Kspan;
  int idx = span[(b * Kspan + k) * 2 + sel];
  const float* src = h + ((size_t)b * Ldim + idx) * Ddim;
  float* dst = hg + (size_t)x * Ddim;
  for (int d = threadIdx.x; d < Ddim; d += 256) dst[d] = src[d];
}

// ---------------- split-bf16 GEMM (multi-job + optional split-K) ------------------------
// MODE 0: relu(acc+bias) f32; MODE 1: acc+bias f32; MODE 2: raw split-K partial;
// MODE 6: both jobs -> bf16 (job0 with bias, job1 raw) — U/V production.
struct GJob {
  const float* A;
  const unsigned short* Wh;
  const unsigned short* Wl;
  const float* bias;
  float* C;
};

template<int MODE, int SPLIT>
__global__ __launch_bounds__(256) void gemm_ms(
    GJob j0, GJob j1, int ldA, int ldW, int ldC, int kLen, size_t csz)
{
  constexpr int SR = 40;
  __shared__ __align__(16) unsigned short Ah[64 * SR], Al[64 * SR];
  __shared__ __align__(16) unsigned short Bh[128 * SR], Bl[128 * SR];
  int zj, s;
  if (SPLIT == 1){ zj = blockIdx.z; s = 0; }
  else { zj = blockIdx.z / SPLIT; s = blockIdx.z % SPLIT; }
  const GJob J = zj ? j1 : j0;
  int kBegin = s * kLen;
  float* Cptr = (MODE == 2) ? (J.C + (size_t)s * csz) : J.C;

  int m0 = blockIdx.y * 64, n0 = blockIdx.x * 128;
  int t = threadIdx.x, lane = t & 63, wid = t >> 6;
  int wm = wid >> 1, wn = wid & 1;
  int lr = lane & 15, lk = (lane >> 4) * 8;
  f32x4 acc[2][4] = {};
  int ar = t >> 2, akq = t & 3;
  for (int k0 = 0; k0 < kLen; k0 += 32){
    {
      const float* sp = J.A + (size_t)(m0 + ar) * ldA + kBegin + k0 + akq * 8;
      f32x4 x0 = *(const f32x4*)sp, x1 = *(const f32x4*)(sp + 4);
      ushort8v vh, vl;
      for (int e = 0; e < 4; e++){ float x = x0[e]; unsigned short hh = f2bf(x); vh[e] = hh; vl[e] = f2bf(x - bf2f(hh)); }
      for (int e = 0; e < 4; e++){ float x = x1[e]; unsigned short hh = f2bf(x); vh[e+4] = hh; vl[e+4] = f2bf(x - bf2f(hh)); }
      *(ushort8v*)&Ah[ar * SR + akq * 8] = vh;
      *(ushort8v*)&Al[ar * SR + akq * 8] = vl;
    }
    for (int p = 0; p < 2; p++){
      int idx = p * 256 + t; int n = idx >> 2, kq = idx & 3;
      size_t go = (size_t)(n0 + n) * ldW + kBegin + k0 + kq * 8;
      *(ushort8v*)&Bh[n * SR + kq * 8] = *(const ushort8v*)(J.Wh + go);
      *(ushort8v*)&Bl[n * SR + kq * 8] = *(const ushort8v*)(J.Wl + go);
    }
    __syncthreads();
    bf16x8 ah[2], al2[2], bh[4], bl[4];
    for (int f = 0; f < 2; f++){ int o = (wm * 32 + f * 16 + lr) * SR + lk; ah[f] = *(const bf16x8*)&Ah[o]; al2[f] = *(const bf16x8*)&Al[o]; }
    for (int g = 0; g < 4; g++){ int o = (wn * 64 + g * 16 + lr) * SR + lk; bh[g] = *(const bf16x8*)&Bh[o]; bl[g] = *(const bf16x8*)&Bl[o]; }
    for (int f = 0; f < 2; f++)
      for (int g = 0; g < 4; g++){
        acc[f][g] = __builtin_amdgcn_mfma_f32_16x16x32_bf16(ah[f],  bh[g], acc[f][g], 0, 0, 0);
        acc[f][g] = __builtin_amdgcn_mfma_f32_16x16x32_bf16(ah[f],  bl[g], acc[f][g], 0, 0, 0);
        acc[f][g] = __builtin_amdgcn_mfma_f32_16x16x32_bf16(al2[f], bh[g], acc[f][g], 0, 0, 0);
      }
    __syncthreads();
  }
  int rr = (lane >> 4) * 4;
  for (int f = 0; f < 2; f++){
    int gm = m0 + wm * 32 + f * 16 + rr;
    for (int g = 0; g < 4; g++){
      int gn = n0 + wn * 64 + g * 16 + (lane & 15);
      float bv = (MODE != 2 && J.bias) ? J.bias[gn] : 0.f;
      for (int r2 = 0; r2 < 4; r2++){
        float v = acc[f][g][r2] + bv;
        if (MODE == 0) v = fmaxf(v, 0.f);
        if (MODE == 6){
          ((unsigned short*)J.C)[(size_t)(gm + r2) * ldC + gn] = f2bf(v);
        } else {
          Cptr[(size_t)(gm + r2) * ldC + gn] = v;
        }
      }
    }
  }
}

// ---------------- split-K partial reduce ----------------
template<bool RELU>
__global__ __launch_bounds__(256) void reduce_part(
    const float* __restrict__ P, int S,
    const float* __restrict__ bias0, const float* __restrict__ bias1,
    float* __restrict__ outp, int zCount, int ldOut)
{
  const int MN = MROWS * Ddim;
  int idx4 = blockIdx.x * 256 + threadIdx.x;
  int flat = idx4 * 4;
  if (flat >= MN * zCount) return;
  int z = flat / MN; int rem = flat - z * MN;
  int r = rem / Ddim; int c = rem - r * Ddim;
  const float* base = P + (size_t)z * S * MN + rem;
  f32x4 sv = *(const f32x4*)base;
  for (int ss = 1; ss < S; ss++){ f32x4 v = *(const f32x4*)(base + (size_t)ss * MN); sv += v; }
  const float* bp = z ? bias1 : bias0;
  f32x4 bv = *(const f32x4*)(bp + c);
  sv += bv;
  if (RELU) for (int e = 0; e < 4; e++) sv[e] = fmaxf(sv[e], 0.f);
  *(f32x4*)(outp + (size_t)r * ldOut + z * Ddim + c) = sv;
}

// ---------------- fused pair GEMM v9 --------------------------------------------------
// v8 architecture (LDS holds ONLY the A tile; B and U/V come from L2 to registers) with
// the scratch bug fixed: NO runtime-indexed register arrays (rule #20).  U-half selection
// is a compile-time-q ternary + one runtime bool -> v_cndmask.  B is loaded at phase
// start and consumed at phase end (no B ping-pong; L2 latency hides under build+afr).
// V/U ping-pong at distance 2 in two NAMED sets.  Regs ~110 VGPR + 96 AGPR -> 2 w/SIMD.
__global__ __launch_bounds__(256, 2) void pair_gemm9(
    const unsigned short* __restrict__ Ub,  // [MROWS][Hdim] bf16, ro_b1 folded
    const unsigned short* __restrict__ Vp,  // [MROWS][Hdim] bf16
    const unsigned short* __restrict__ W2B, // frag-packed per (nq,kt), 4096 shorts
    const float* __restrict__ b2,           // [Ddim]
    float* __restrict__ out)                // [Bdim*Pdim][Ddim]
{
  __shared__ __align__(16) unsigned short As[2][192 * 32]; // 2 x 12 KiB

  int x = blockIdx.x;
  int xcd = x & 7;
  int s = x >> 3;                 // 0..143
  int grp = s / 48;
  int ig  = s - grp * 48;
  int combo = xcd + grp * 8;      // 0..23
  int nq = combo % 6, b = combo / 6;

  int t = threadIdx.x, lane = t & 63, w = t >> 6;
  int wm = w >> 1, wn = w & 1;
  int l31 = lane & 31, hsel = lane >> 5;
  int i0 = ig * 2, i = i0 + wm;

  // builder: 3 rows brow, brow+64, brow+128; fixed granule bg = t&3
  int brow = t >> 2, bg = t & 3;
  bool hiMid = (brow >= 32);      // row brow+64 >= 96 ?
  int vj0 = brow;                                   // < 96
  int vj1 = hiMid ? (brow - 32) : (brow + 64);      // (brow+64) mod 96
  int vj2 = brow + 32;                              // (brow+128)-96

  f32x16 acc[3][2] = {};
  ushort8v vA0, vA1, vA2, uA0, uA1;   // set A (even tiles)
  ushort8v vB0, vB1, vB2, uB0, uB1;   // set B (odd tiles)

  const unsigned short* Vbase = Vp + (size_t)(b * 96) * Hdim + bg * 8;
  const unsigned short* Ubase = Ub + (size_t)(b * 96 + i0) * Hdim + bg * 8;
  const unsigned short* Wt = W2B + (size_t)(nq * 96) * 4096 + wn * 2048 + hsel * 256 + l31 * 8;
  unsigned short* const As0 = &As[0][0];
  unsigned short* const As1 = &As[1][0];

  #define LOADVU(KT, V0, V1, V2, U0, U1) { \
    int koff = (KT) * 32; \
    V0 = *(const ushort8v*)(Vbase + (size_t)vj0 * Hdim + koff); \
    V1 = *(const ushort8v*)(Vbase + (size_t)vj1 * Hdim + koff); \
    V2 = *(const ushort8v*)(Vbase + (size_t)vj2 * Hdim + koff); \
    U0 = *(const ushort8v*)(Ubase + koff); \
    U1 = *(const ushort8v*)(Ubase + Hdim + koff); \
  }
  #define LOADB(KT, BB) { \
    const unsigned short* p_ = Wt + (size_t)(KT) * 4096; \
    BB[0] = *(const ushort8v*)(p_); \
    BB[1] = *(const ushort8v*)(p_ + 512); \
    BB[2] = *(const ushort8v*)(p_ + 1024); \
    BB[3] = *(const ushort8v*)(p_ + 1536); \
  }
  // build: row q uses U-half {0, hiMid, 1} -- compile-time q, runtime bool only.
  #define BUILD(DP, V0, V1, V2, U0, U1) { \
    ushort8v um_ = hiMid ? (U1) : (U0); \
    _Pragma("unroll") \
    for (int q = 0; q < 3; q++){ \
      int r_ = brow + 64 * q; \
      ushort8v uu = (q == 0) ? (U0) : ((q == 2) ? (U1) : um_); \
      ushort8v vv = (q == 0) ? (V0) : ((q == 2) ? (V2) : (V1)); \
      ushort8v pk; \
      _Pragma("unroll") \
      for (int e = 0; e < 8; e++) \
        pk[e] = f2bf(fmaxf(bfbits2f(uu[e]) + bfbits2f(vv[e]), 0.f)); \
      *(ushort8v*)((DP) + r_ * 32 + ((bg ^ ((r_ >> 1) & 3)) << 3)) = pk; \
    } \
  }

  auto compute = [&](const unsigned short* ap, const ushort8v* bfrag){
    #pragma unroll
    for (int kh = 0; kh < 2; kh++){
      int g = kh * 2 + hsel;
      bf16x8 afr[3];
      #pragma unroll
      for (int mf = 0; mf < 3; mf++){
        int r = wm * 96 + mf * 32 + l31;
        afr[mf] = *(const bf16x8*)(ap + r * 32 + ((g ^ ((r >> 1) & 3)) << 3));
      }
      #pragma unroll
      for (int mf = 0; mf < 3; mf++)
        #pragma unroll
        for (int nf = 0; nf < 2; nf++)
          acc[mf][nf] = __builtin_amdgcn_mfma_f32_32x32x16_bf16(
              afr[mf], __builtin_bit_cast(bf16x8, bfrag[kh * 2 + nf]), acc[mf][nf], 0, 0, 0);
    }
  };

  // prologue: tiles 0 (set A) and 1 (set B); build tile 0
  LOADVU(0, vA0, vA1, vA2, uA0, uA1);
  LOADVU(1, vB0, vB1, vB2, uB0, uB1);
  BUILD(As0, vA0, vA1, vA2, uA0, uA1);
  __syncthreads();               // As[0] visible

  for (int kt = 0; kt < NT6; kt += 2){
    // even phase: compute tile kt (As0); build kt+1 (set B) -> As1; load kt+2 -> set A
    {
      ushort8v bb[4];
      LOADB(kt, bb);
      if (kt + 2 < NT6) LOADVU(kt + 2, vA0, vA1, vA2, uA0, uA1);
      if (kt + 1 < NT6) BUILD(As1, vB0, vB1, vB2, uB0, uB1);
      compute(As0, bb);
      __syncthreads();
    }
    // odd phase: compute tile kt+1 (As1); build kt+2 (set A) -> As0; load kt+3 -> set B
    {
      int ko = kt + 1;
      ushort8v bb[4];
      LOADB(ko, bb);
      if (ko + 2 < NT6) LOADVU(ko + 2, vB0, vB1, vB2, uB0, uB1);
      if (ko + 1 < NT6) BUILD(As0, vA0, vA1, vA2, uA0, uA1);
      compute(As1, bb);
      __syncthreads();
    }
  }

  // epilogue: wave wm -> i; row j -> pair p = i*95 + j - (j>i); skip j==i
  size_t outB = (size_t)b * Pdim;
  int colbase = nq * 128 + wn * 64;
  float bc[2];
  #pragma unroll
  for (int nf = 0; nf < 2; nf++) bc[nf] = b2[colbase + nf * 32 + l31];
  #pragma unroll
  for (int mf = 0; mf < 3; mf++){
    #pragma unroll
    for (int reg = 0; reg < 16; reg++){
      int j = mf * 32 + (reg & 3) + 8 * (reg >> 2) + 4 * hsel;
      if (j == i) continue;
      int p = i * 95 + j - (j > i ? 1 : 0);
      float* orow = out + (outB + p) * Ddim + colbase;
      #pragma unroll
      for (int nf = 0; nf < 2; nf++)
        orow[nf * 32 + l31] = acc[mf][nf][reg] + bc[nf];
    }
  }
  #undef LOADVU
  #undef LOADB
  #undef BUILD
}

// ---------------- host launch ----------------
extern "C" void kernel_launch(void* const* d_in, const int* in_sizes, int n_in,
                              void* d_out, int out_size, void* d_ws, size_t ws_size,
                              hipStream_t stream)
{
  (void)in_sizes; (void)n_in; (void)out_size;
  const float* h     = (const float*)d_in[0];
  const int*   span  = (const int*)d_in[1];
  const float* ps_w1 = (const float*)d_in[2];
  const float* ps_b1 = (const float*)d_in[3];
  const float* ps_w2 = (const float*)d_in[4];
  const float* ps_b2 = (const float*)d_in[5];
  const float* pe_w1 = (const float*)d_in[6];
  const float* pe_b1 = (const float*)d_in[7];
  const float* pe_w2 = (const float*)d_in[8];
  const float* pe_b2 = (const float*)d_in[9];
  const float* so_w1 = (const float*)d_in[10];
  const float* so_b1 = (const float*)d_in[11];
  const float* so_w2 = (const float*)d_in[12];
  const float* so_b2 = (const float*)d_in[13];
  const float* ro_w1 = (const float*)d_in[14];
  const float* ro_b1 = (const float*)d_in[15];
  const float* ro_w2 = (const float*)d_in[16];
  const float* ro_b2 = (const float*)d_in[17];

  char* ws = (char*)d_ws;
  size_t off = 0;
  auto alloc_us = [&](size_t n)->unsigned short*{
    unsigned short* p = (unsigned short*)(ws + off);
    off += ((n * 2 + 255) & ~(size_t)255);
    return p;
  };
  auto alloc_f = [&](size_t n)->float*{
    float* p = (float*)(ws + off);
    off += ((n * 4 + 255) & ~(size_t)255);
    return p;
  };

  unsigned short* ps1h = alloc_us((size_t)Hdim * Ddim); unsigned short* ps1l = alloc_us((size_t)Hdim * Ddim);
  unsigned short* ps2h = alloc_us((size_t)Ddim * Hdim); unsigned short* ps2l = alloc_us((size_t)Ddim * Hdim);
  unsigned short* pe1h = alloc_us((size_t)Hdim * Ddim); unsigned short* pe1l = alloc_us((size_t)Hdim * Ddim);
  unsigned short* pe2h = alloc_us((size_t)Ddim * Hdim); unsigned short* pe2l = alloc_us((size_t)Ddim * Hdim);
  unsigned short* so1h = alloc_us((size_t)Hdim * 2 * Ddim); unsigned short* so1l = alloc_us((size_t)Hdim * 2 * Ddim);
  unsigned short* so2h = alloc_us((size_t)Ddim * Hdim); unsigned short* so2l = alloc_us((size_t)Ddim * Hdim);
  unsigned short* ro1h = alloc_us((size_t)Hdim * 2 * Ddim); unsigned short* ro1l = alloc_us((size_t)Hdim * 2 * Ddim);
  unsigned short* W2B  = alloc_us((size_t)6 * 96 * 4096);   // 2.36M shorts
  unsigned short* Vp   = alloc_us((size_t)MROWS * Hdim);    // bf16 V
  unsigned short* Ub   = alloc_us((size_t)MROWS * Hdim);    // bf16 U (ro_b1 folded)
  float* hg     = alloc_f((size_t)2 * MROWS * Ddim);
  float* mid_s  = alloc_f((size_t)MROWS * Hdim);
  float* mid_e  = alloc_f((size_t)MROWS * Hdim);
  float* cat    = alloc_f((size_t)MROWS * 2 * Ddim);
  float* entity = alloc_f((size_t)MROWS * Ddim);
  const size_t MN = (size_t)MROWS * Ddim;
  float* P2 = alloc_f(8 * MN);
  float* P3 = alloc_f(8 * MN);
  if (off > ws_size) return;

  dim3 tb(256);

  // merged weight transposes (7 jobs)
  {
    TJobs JJ;
    int base = 0;
    auto add = [&](int idx, const float* W, unsigned short* Th, unsigned short* Tl, int K, int N){
      JJ.j[idx] = TJob{W, Th, Tl, K, N, base};
      base += (N / 64) * (K / 64);
    };
    add(0, ps_w1, ps1h, ps1l, Ddim, Hdim);
    add(1, ps_w2, ps2h, ps2l, Hdim, Ddim);
    add(2, pe_w1, pe1h, pe1l, Ddim, Hdim);
    add(3, pe_w2, pe2h, pe2l, Hdim, Ddim);
    add(4, so_w1, so1h, so1l, 2 * Ddim, Hdim);
    add(5, so_w2, so2h, so2l, Hdim, Ddim);
    add(6, ro_w1, ro1h, ro1l, 2 * Ddim, Hdim);
    transpose_multi<<<base, tb, 0, stream>>>(JJ);
  }
  pack_w2<<<dim3(NT6, 6), tb, 0, stream>>>(ro_w2, W2B);

  gather_rows<<<2 * MROWS, tb, 0, stream>>>(h, span, hg);

  // L1: start/end first linear (merged), M=384 N=3072 K=768
  {
    GJob j0{hg,                      ps1h, ps1l, ps_b1, mid_s};
    GJob j1{hg + (size_t)MROWS*Ddim, pe1h, pe1l, pe_b1, mid_e};
    gemm_ms<0,1><<<dim3(Hdim/128, MROWS/64, 2), tb, 0, stream>>>(j0, j1, Ddim, Ddim, Hdim, Ddim, 0);
  }
  // L2: start/end second linear (merged, split-K=4) -> partials
  {
    GJob j0{mid_s, ps2h, ps2l, nullptr, P2};
    GJob j1{mid_e, pe2h, pe2l, nullptr, P2 + 4*MN};
    gemm_ms<2,4><<<dim3(Ddim/128, MROWS/64, 8), tb, 0, stream>>>(j0, j1, Hdim, Hdim, Ddim, Hdim/4, MN);
  }
  reduce_part<true><<<(2*(int)MN)/1024, tb, 0, stream>>>(P2, 4, ps_b2, pe_b2, cat, 2, 2*Ddim);
  // so1: M=384 N=3072 K=1536
  {
    GJob j0{cat, so1h, so1l, so_b1, mid_s};
    gemm_ms<0,1><<<dim3(Hdim/128, MROWS/64, 1), tb, 0, stream>>>(j0, j0, 2*Ddim, 2*Ddim, Hdim, 2*Ddim, 0);
  }
  // so2: split-K=8 -> partials (no relu on entity)
  {
    GJob j0{mid_s, so2h, so2l, nullptr, P3};
    gemm_ms<2,8><<<dim3(Ddim/128, MROWS/64, 8), tb, 0, stream>>>(j0, j0, Hdim, Hdim, Ddim, Hdim/8, MN);
  }
  reduce_part<false><<<((int)MN)/1024, tb, 0, stream>>>(P3, 8, so_b2, so_b2, entity, 1, Ddim);
  // U = entity @ ro_w1_top + ro_b1 ; V = entity @ ro_w1_bot — both bf16 (MODE 6)
  {
    GJob j0{entity, ro1h,        ro1l,        ro_b1,  (float*)Ub};
    GJob j1{entity, ro1h + Ddim, ro1l + Ddim, nullptr, (float*)Vp};
    gemm_ms<6,1><<<dim3(Hdim/128, MROWS/64, 2), tb, 0, stream>>>(j0, j1, Ddim, 2*Ddim, Hdim, Ddim, 0);
  }

  // fused pair GEMM v9
  pair_gemm9<<<1152, tb, 0, stream>>>(Ub, Vp, W2B, ro_b2, (float*)d_out);
}